// Round 1
// baseline (262.651 us; speedup 1.0000x reference)
//
#include <hip/hip_runtime.h>
#include <hip/hip_bf16.h>

#define E_ 8
#define D_ 1024
#define H_ 4096
#define T_ 512
#define A_ 1024  // total assignments = T_ * top_k

typedef __attribute__((ext_vector_type(8))) short bf16x8;
typedef __attribute__((ext_vector_type(4))) float f32x4;

__device__ __forceinline__ unsigned short f2bf(float f) {
  __hip_bfloat16 h = __float2bfloat16(f);
  return *reinterpret_cast<unsigned short*>(&h);
}

// ---------------- Router: logits -> softmax -> top2 -> renorm; x -> bf16 ----
__global__ void moe_router(const float* __restrict__ x,
                           const float* __restrict__ gw,
                           unsigned short* __restrict__ xb,
                           int* __restrict__ sel,
                           float* __restrict__ wtop) {
  const int t = blockIdx.x;
  const int lane = threadIdx.x;  // 64 threads
  const float* xr = x + (size_t)t * D_;

  // bf16 copy of x row
  for (int i = lane; i < D_; i += 64) xb[(size_t)t * D_ + i] = f2bf(xr[i]);

  float lg[E_];
  for (int e = 0; e < E_; ++e) {
    const float* g = gw + (size_t)e * D_;
    float p = 0.f;
    for (int i = lane; i < D_; i += 64) p += xr[i] * g[i];
#pragma unroll
    for (int off = 32; off; off >>= 1) p += __shfl_xor(p, off);
    lg[e] = p;
  }
  if (lane == 0) {
    float m = lg[0];
    for (int e = 1; e < E_; ++e) m = fmaxf(m, lg[e]);
    float pr[E_];
    float s = 0.f;
    for (int e = 0; e < E_; ++e) { pr[e] = __expf(lg[e] - m); s += pr[e]; }
    const float inv = 1.f / s;
    for (int e = 0; e < E_; ++e) pr[e] *= inv;
    // top-2, ties -> lower index (matches jax.lax.top_k)
    float v0 = -1.f, v1 = -1.f; int i0 = 0, i1 = 0;
    for (int e = 0; e < E_; ++e) {
      float p = pr[e];
      if (p > v0)      { v1 = v0; i1 = i0; v0 = p; i0 = e; }
      else if (p > v1) { v1 = p; i1 = e; }
    }
    const float s2 = 1.f / (v0 + v1);
    sel[2 * t] = i0; sel[2 * t + 1] = i1;
    wtop[2 * t] = v0 * s2; wtop[2 * t + 1] = v1 * s2;
  }
}

// ---------------- Compaction: deterministic, order-preserving ---------------
__global__ void moe_compact(const int* __restrict__ sel,
                            const float* __restrict__ wtop,
                            int* __restrict__ counts,
                            int* __restrict__ offsets,
                            int* __restrict__ tok,
                            int* __restrict__ slotof,
                            float* __restrict__ coef) {
  const int tid = threadIdx.x;         // 512 threads = 8 waves
  const int e = tid >> 6;              // wave id = expert
  const int lane = tid & 63;
  __shared__ int cnt[E_], offs[E_];

  int base = 0;
  for (int c = 0; c < T_ / 64; ++c) {
    const int t = c * 64 + lane;
    const int s0 = sel[2 * t], s1 = sel[2 * t + 1];
    const bool f = (s0 == e) || (s1 == e);
    unsigned long long b = __ballot(f);
    base += __popcll(b);
  }
  if (lane == 0) cnt[e] = base;
  __syncthreads();
  if (tid == 0) {
    int o = 0;
    for (int i = 0; i < E_; ++i) { offs[i] = o; o += cnt[i]; }
  }
  __syncthreads();
  if (lane == 0) { counts[e] = cnt[e]; offsets[e] = offs[e]; }

  int pos = offs[e];
  for (int c = 0; c < T_ / 64; ++c) {
    const int t = c * 64 + lane;
    const int s0 = sel[2 * t], s1 = sel[2 * t + 1];
    const bool f = (s0 == e) || (s1 == e);
    unsigned long long b = __ballot(f);
    const int myp = pos + __popcll(b & ((1ull << lane) - 1ull));
    if (f) {
      const int k = (s0 == e) ? 0 : 1;
      tok[myp] = t;
      slotof[2 * t + k] = myp;
      coef[myp] = wtop[2 * t + k];
    }
    pos += __popcll(b);
  }
}

// ---------------- Grouped GEMM tiles --------------------------------------
#define BM 128
#define BN 128
#define BK 64
#define LDK 72  // +8 bf16 pad (keeps 16B alignment, breaks bank aliasing)

// act[g][h] = silu(x@w1^T) * (x@w3^T) for each assignment row g
__launch_bounds__(256)
__global__ void moe_ffn1(const unsigned short* __restrict__ xb,
                         const float* __restrict__ w1,
                         const float* __restrict__ w3,
                         const int* __restrict__ counts,
                         const int* __restrict__ offsets,
                         const int* __restrict__ tok,
                         unsigned short* __restrict__ act) {
  const int bid = blockIdx.x;
  const int e = bid >> 7;            // 4 row-tiles * 32 h-tiles per expert
  const int mt = (bid >> 5) & 3;
  const int ht = bid & 31;
  const int count = counts[e];
  if (mt * BM >= count) return;
  const int off = offsets[e];

  __shared__ unsigned short As[BM][LDK];
  __shared__ unsigned short B1s[BN][LDK];
  __shared__ unsigned short B3s[BN][LDK];

  const int tid = threadIdx.x;
  const int lane = tid & 63, wid = tid >> 6;
  const int wr = (wid >> 1) * 64, wc = (wid & 1) * 64;

  f32x4 acc1[4][4] = {};
  f32x4 acc3[4][4] = {};

  const float* W1 = w1 + (size_t)e * H_ * D_ + (size_t)(ht * BN) * D_;
  const float* W3 = w3 + (size_t)e * H_ * D_ + (size_t)(ht * BN) * D_;

  // Precompute token row base per staged A chunk (loop-invariant over kt)
  const unsigned short* arow[4];
#pragma unroll
  for (int i = 0; i < 4; ++i) {
    const int c = tid + 256 * i;
    const int r = c >> 3;
    const int m = mt * BM + r;
    const int slot = off + (m < count ? m : 0);
    arow[i] = xb + (size_t)tok[slot] * D_;
  }

  for (int kt = 0; kt < D_; kt += BK) {
    __syncthreads();
    // A tile: 128x64 bf16, 4 chunks of 8 bf16 per thread
#pragma unroll
    for (int i = 0; i < 4; ++i) {
      const int c = tid + 256 * i;
      const int r = c >> 3, c8 = c & 7;
      float4 v = *reinterpret_cast<const float4*>(arow[i] + kt + c8 * 8);
      *reinterpret_cast<float4*>(&As[r][c8 * 8]) = v;
    }
    // B tiles: 128 rows x 64 fp32 each for w1 and w3, convert to bf16
#pragma unroll
    for (int i = 0; i < 8; ++i) {
      const int c = tid + 256 * i;
      const int r = c >> 4, c4 = c & 15;
      float4 v1 = *reinterpret_cast<const float4*>(W1 + (size_t)r * D_ + kt + c4 * 4);
      float4 v3 = *reinterpret_cast<const float4*>(W3 + (size_t)r * D_ + kt + c4 * 4);
      ushort4 b1, b3;
      b1.x = f2bf(v1.x); b1.y = f2bf(v1.y); b1.z = f2bf(v1.z); b1.w = f2bf(v1.w);
      b3.x = f2bf(v3.x); b3.y = f2bf(v3.y); b3.z = f2bf(v3.z); b3.w = f2bf(v3.w);
      *reinterpret_cast<ushort4*>(&B1s[r][c4 * 4]) = b1;
      *reinterpret_cast<ushort4*>(&B3s[r][c4 * 4]) = b3;
    }
    __syncthreads();

#pragma unroll
    for (int ks = 0; ks < BK; ks += 32) {
      const int krow = ks + (lane >> 4) * 8;
      bf16x8 af[4];
#pragma unroll
      for (int m = 0; m < 4; ++m)
        af[m] = *reinterpret_cast<const bf16x8*>(&As[wr + m * 16 + (lane & 15)][krow]);
#pragma unroll
      for (int n = 0; n < 4; ++n) {
        bf16x8 b1f = *reinterpret_cast<const bf16x8*>(&B1s[wc + n * 16 + (lane & 15)][krow]);
        bf16x8 b3f = *reinterpret_cast<const bf16x8*>(&B3s[wc + n * 16 + (lane & 15)][krow]);
#pragma unroll
        for (int m = 0; m < 4; ++m) {
          acc1[m][n] = __builtin_amdgcn_mfma_f32_16x16x32_bf16(af[m], b1f, acc1[m][n], 0, 0, 0);
          acc3[m][n] = __builtin_amdgcn_mfma_f32_16x16x32_bf16(af[m], b3f, acc3[m][n], 0, 0, 0);
        }
      }
    }
  }

  // Epilogue: silu(h1)*h3 -> bf16 act
  const int rbase = (lane >> 4) * 4;
  const int cbase = lane & 15;
#pragma unroll
  for (int m = 0; m < 4; ++m) {
#pragma unroll
    for (int r = 0; r < 4; ++r) {
      const int mrow = mt * BM + wr + m * 16 + rbase + r;
      if (mrow < count) {
        const size_t rowp = (size_t)(off + mrow) * H_;
#pragma unroll
        for (int n = 0; n < 4; ++n) {
          const float h1 = acc1[m][n][r];
          const float h3 = acc3[m][n][r];
          const float a = h1 / (1.f + __expf(-h1)) * h3;
          const int hcol = ht * BN + wc + n * 16 + cbase;
          act[rowp + hcol] = f2bf(a);
        }
      }
    }
  }
}

// part[g][d] = coef[g] * (act[g] @ w2[e]^T)
__launch_bounds__(256)
__global__ void moe_ffn2(const unsigned short* __restrict__ act,
                         const float* __restrict__ w2,
                         const int* __restrict__ counts,
                         const int* __restrict__ offsets,
                         const float* __restrict__ coef,
                         float* __restrict__ part) {
  const int bid = blockIdx.x;
  const int e = bid >> 5;            // 4 row-tiles * 8 d-tiles per expert
  const int mt = (bid >> 3) & 3;
  const int dt = bid & 7;
  const int count = counts[e];
  if (mt * BM >= count) return;
  const int off = offsets[e];

  __shared__ unsigned short As[BM][LDK];
  __shared__ unsigned short Bs[BN][LDK];

  const int tid = threadIdx.x;
  const int lane = tid & 63, wid = tid >> 6;
  const int wr = (wid >> 1) * 64, wc = (wid & 1) * 64;

  f32x4 acc[4][4] = {};

  const float* W2 = w2 + (size_t)e * D_ * H_ + (size_t)(dt * BN) * H_;

  const unsigned short* arow[4];
#pragma unroll
  for (int i = 0; i < 4; ++i) {
    const int c = tid + 256 * i;
    const int r = c >> 3;
    const int m = mt * BM + r;
    const int slot = off + (m < count ? m : 0);
    arow[i] = act + (size_t)slot * H_;
  }

  for (int kt = 0; kt < H_; kt += BK) {
    __syncthreads();
#pragma unroll
    for (int i = 0; i < 4; ++i) {
      const int c = tid + 256 * i;
      const int r = c >> 3, c8 = c & 7;
      float4 v = *reinterpret_cast<const float4*>(arow[i] + kt + c8 * 8);
      *reinterpret_cast<float4*>(&As[r][c8 * 8]) = v;
    }
#pragma unroll
    for (int i = 0; i < 8; ++i) {
      const int c = tid + 256 * i;
      const int r = c >> 4, c4 = c & 15;
      float4 v = *reinterpret_cast<const float4*>(W2 + (size_t)r * H_ + kt + c4 * 4);
      ushort4 b;
      b.x = f2bf(v.x); b.y = f2bf(v.y); b.z = f2bf(v.z); b.w = f2bf(v.w);
      *reinterpret_cast<ushort4*>(&Bs[r][c4 * 4]) = b;
    }
    __syncthreads();

#pragma unroll
    for (int ks = 0; ks < BK; ks += 32) {
      const int krow = ks + (lane >> 4) * 8;
      bf16x8 af[4];
#pragma unroll
      for (int m = 0; m < 4; ++m)
        af[m] = *reinterpret_cast<const bf16x8*>(&As[wr + m * 16 + (lane & 15)][krow]);
#pragma unroll
      for (int n = 0; n < 4; ++n) {
        bf16x8 bf = *reinterpret_cast<const bf16x8*>(&Bs[wc + n * 16 + (lane & 15)][krow]);
#pragma unroll
        for (int m = 0; m < 4; ++m)
          acc[m][n] = __builtin_amdgcn_mfma_f32_16x16x32_bf16(af[m], bf, acc[m][n], 0, 0, 0);
      }
    }
  }

  const int rbase = (lane >> 4) * 4;
  const int cbase = lane & 15;
#pragma unroll
  for (int m = 0; m < 4; ++m) {
#pragma unroll
    for (int r = 0; r < 4; ++r) {
      const int mrow = mt * BM + wr + m * 16 + rbase + r;
      if (mrow < count) {
        const float cf = coef[off + mrow];
        float* prow = part + (size_t)(off + mrow) * D_;
#pragma unroll
        for (int n = 0; n < 4; ++n) {
          const int dcol = dt * BN + wc + n * 16 + cbase;
          prow[dcol] = cf * acc[m][n][r];
        }
      }
    }
  }
}

// out[t] = part[slot0(t)] + part[slot1(t)]  (fixed order -> deterministic)
__global__ void moe_combine(const float* __restrict__ part,
                            const int* __restrict__ slotof,
                            float* __restrict__ out) {
  const int t = blockIdx.x;
  const int i = threadIdx.x;  // 256 threads, float4 each
  const int g0 = slotof[2 * t], g1 = slotof[2 * t + 1];
  float4 a = reinterpret_cast<const float4*>(part + (size_t)g0 * D_)[i];
  float4 b = reinterpret_cast<const float4*>(part + (size_t)g1 * D_)[i];
  float4 o;
  o.x = a.x + b.x; o.y = a.y + b.y; o.z = a.z + b.z; o.w = a.w + b.w;
  reinterpret_cast<float4*>(out + (size_t)t * D_)[i] = o;
}

extern "C" void kernel_launch(void* const* d_in, const int* in_sizes, int n_in,
                              void* d_out, int out_size, void* d_ws, size_t ws_size,
                              hipStream_t stream) {
  const float* x  = (const float*)d_in[0];
  const float* gw = (const float*)d_in[1];
  const float* w1 = (const float*)d_in[2];
  const float* w3 = (const float*)d_in[3];
  const float* w2 = (const float*)d_in[4];
  float* out = (float*)d_out;

  char* ws = (char*)d_ws;
  // ws layout (total ~14.7 MB)
  unsigned short* xb   = (unsigned short*)(ws + 0);         // 512*1024 bf16 = 1 MB
  int*   sel     = (int*)  (ws + 1048576);                  // 1024 ints
  float* wtop    = (float*)(ws + 1052672);                  // 1024 floats
  int*   counts  = (int*)  (ws + 1056768);                  // 8
  int*   offsets = (int*)  (ws + 1056800);                  // 8
  int*   tokl    = (int*)  (ws + 1056832);                  // 1024
  int*   slotof  = (int*)  (ws + 1060928);                  // 1024
  float* coef    = (float*)(ws + 1065024);                  // 1024
  unsigned short* act = (unsigned short*)(ws + 2097152);    // 1024*4096 bf16 = 8 MB
  float* part    = (float*)(ws + 10485760);                 // 1024*1024 f32 = 4 MB

  moe_router <<<T_, 64, 0, stream>>>(x, gw, xb, sel, wtop);
  moe_compact<<<1, 512, 0, stream>>>(sel, wtop, counts, offsets, tokl, slotof, coef);
  moe_ffn1   <<<E_ * 4 * 32, 256, 0, stream>>>(xb, w1, w3, counts, offsets, tokl, act);
  moe_ffn2   <<<E_ * 4 * 8, 256, 0, stream>>>(act, w2, counts, offsets, coef, part);
  moe_combine<<<T_, 256, 0, stream>>>(part, slotof, out);
}